// Round 15
// baseline (209.421 us; speedup 1.0000x reference)
//
#include <hip/hip_runtime.h>
#include <hip/hip_fp8.h>

#define N_IN 64
#define HID 128
#define OUT_F 64
#define EPB 12288         // edges per partition block (48 iters x 256)
#define BKT 128           // nodes per bucket (pow2; dlocal fits 7 bits)

typedef unsigned short ushort_t;
typedef unsigned char  uchar_t;
typedef ushort_t us8  __attribute__((ext_vector_type(8)));
typedef uchar_t  uc8  __attribute__((ext_vector_type(8)));
typedef short    s16x8 __attribute__((ext_vector_type(8)));
typedef float    f32x4 __attribute__((ext_vector_type(4)));
typedef float    f32x2 __attribute__((ext_vector_type(2)));
typedef unsigned int uint2v __attribute__((ext_vector_type(2)));

__device__ inline ushort_t f2bf(float f) {          // round-to-nearest-even
    unsigned u = __float_as_uint(f);
    u = u + 0x7fffu + ((u >> 16) & 1u);
    return (ushort_t)(u >> 16);
}
__device__ inline float bf2f(ushort_t b) {
    return __uint_as_float((unsigned)b << 16);
}
__device__ inline uchar_t f2fp8(float v) {          // OCP e4m3
    __hip_fp8_e4m3 q(v);
    return (uchar_t)q.__x;
}
template<bool HI>
__device__ inline f32x2 fp8pair(unsigned int dw) {
#if __has_builtin(__builtin_amdgcn_cvt_pk_f32_fp8)
    auto r = __builtin_amdgcn_cvt_pk_f32_fp8(dw, HI);   // HI is a literal
    f32x2 o; o[0] = r[0]; o[1] = r[1];
    return o;
#else
    f32x2 o;
#pragma unroll
    for (int i = 0; i < 2; ++i) {
        __hip_fp8_e4m3 h; h.__x = (dw >> (8 * (2 * (int)HI + i))) & 0xff;
        o[i] = (float)h;
    }
    return o;
#endif
}

// ---------------------------------------------------------------------------
// fused prep:
//   [0,BA)   feat fp32 -> bf16 + fp8
//   [BA,BB)  weights -> bf16 transposed
//   [BB,BC)  pass A: per-block bucket histogram (LDS atomics only)
// ---------------------------------------------------------------------------
__global__ __launch_bounds__(256)
void prep_kernel(const float* __restrict__ feat, ushort_t* __restrict__ featb,
                 uchar_t* __restrict__ featq, int n8,
                 const float* __restrict__ Ws1, const float* __restrict__ Wn1,
                 const float* __restrict__ Ws2, const float* __restrict__ Wn2,
                 const float* __restrict__ Wm1, const float* __restrict__ Wm2,
                 ushort_t* __restrict__ wsT1, ushort_t* __restrict__ wnT1,
                 ushort_t* __restrict__ wsT2, ushort_t* __restrict__ wnT2,
                 ushort_t* __restrict__ wmT1, ushort_t* __restrict__ wmT2,
                 const int* __restrict__ dst, int* __restrict__ histT,
                 int E, int nbuk, int nba, int BA, int BB) {
    __shared__ int hist[800];
    int b = blockIdx.x;
    int tid = threadIdx.x;
    if (b < BA) {
        int i = b * 256 + tid;
        if (i >= n8) return;
        f32x4 a = ((const f32x4*)feat)[2 * i];
        f32x4 c = ((const f32x4*)feat)[2 * i + 1];
        us8 v; uc8 q;
#pragma unroll
        for (int t = 0; t < 4; ++t) {
            v[t] = f2bf(a[t]); v[4 + t] = f2bf(c[t]);
            q[t] = f2fp8(a[t]); q[4 + t] = f2fp8(c[t]);
        }
        ((us8*)featb)[i] = v;
        ((uc8*)featq)[i] = q;
    } else if (b < BB) {
        int i = (b - BA) * 256 + tid;
        const float* W; ushort_t* WT; int K, H, l;
        if      (i < 8192)  { W = Ws1; WT = wsT1; K = 64;  H = 128; l = i; }
        else if (i < 16384) { W = Wn1; WT = wnT1; K = 64;  H = 128; l = i - 8192; }
        else if (i < 32768) { W = Ws2; WT = wsT2; K = 128; H = 128; l = i - 16384; }
        else if (i < 49152) { W = Wn2; WT = wnT2; K = 128; H = 128; l = i - 32768; }
        else if (i < 65536) { W = Wm1; WT = wmT1; K = 128; H = 128; l = i - 49152; }
        else if (i < 73728) { W = Wm2; WT = wmT2; K = 128; H = 64;  l = i - 65536; }
        else return;
        int h = l / K, k = l % K;
        WT[l] = f2bf(W[(size_t)k * H + h]);
    } else {
        const int blk  = b - BB;
        const int base = blk * EPB;
        for (int k = tid; k < nbuk; k += 256) hist[k] = 0;
        __syncthreads();
#pragma unroll 4
        for (int it = 0; it < EPB / 256; ++it) {
            int e = base + it * 256 + tid;
            if (e < E) atomicAdd(&hist[(unsigned)dst[e] / BKT], 1);
        }
        __syncthreads();
        for (int k = tid; k < nbuk; k += 256)
            histT[(size_t)k * nba + blk] = hist[k];
    }
}

// ---------------------------------------------------------------------------
// scan (2 kernels): per-256 block exclusive scan; partials exclusive scan.
// consumers add partials[idx>>8] themselves (scan_add folded away).
// ---------------------------------------------------------------------------
__global__ __launch_bounds__(256)
void scan_block(const int* __restrict__ in, int* __restrict__ out,
                int* __restrict__ partials, int n) {
    __shared__ int sm[256];
    int i = blockIdx.x * 256 + threadIdx.x;
    int v = (i < n) ? in[i] : 0;
    sm[threadIdx.x] = v;
    __syncthreads();
    for (int d = 1; d < 256; d <<= 1) {
        int t = (threadIdx.x >= d) ? sm[threadIdx.x - d] : 0;
        __syncthreads();
        sm[threadIdx.x] += t;
        __syncthreads();
    }
    if (i < n) out[i] = sm[threadIdx.x] - v;
    if (threadIdx.x == 255) partials[blockIdx.x] = sm[255];
}

__global__ __launch_bounds__(1024)
void scan_partials(int* __restrict__ partials, int nparts) {
    __shared__ int sm[1024];
    int i = threadIdx.x;
    int v = (i < nparts) ? partials[i] : 0;
    sm[i] = v;
    __syncthreads();
    for (int d = 1; d < 1024; d <<= 1) {
        int t = (i >= d) ? sm[i - d] : 0;
        __syncthreads();
        sm[i] += t;
        __syncthreads();
    }
    if (i < nparts) partials[i] = sm[i] - v;
}

// ---------------------------------------------------------------------------
// pass C: bucket-partition edges; u32-packed (dlocal<<17 | src); LDS cursors
// ---------------------------------------------------------------------------
__global__ __launch_bounds__(256)
void part_edges(const int* __restrict__ src, const int* __restrict__ dst,
                const int* __restrict__ histT, const int* __restrict__ partials,
                unsigned* __restrict__ epk, int E, int nbuk, int nba) {
    __shared__ int cur[800];
    const int blk  = blockIdx.x;
    const int base = blk * EPB;
    const int tid  = threadIdx.x;
    for (int k = tid; k < nbuk; k += 256) {
        size_t idx = (size_t)k * nba + blk;
        cur[k] = histT[idx] + partials[idx >> 8];
    }
    __syncthreads();
#pragma unroll 4
    for (int it = 0; it < EPB / 256; ++it) {
        int e = base + it * 256 + tid;
        if (e < E) {
            unsigned d = (unsigned)dst[e], s = (unsigned)src[e];
            int pos = atomicAdd(&cur[d / BKT], 1);
            epk[pos] = ((d & (BKT - 1)) << 17) | s;     // nn < 2^17
        }
    }
}

// ---------------------------------------------------------------------------
// pass D: per-bucket CSR finalize (BKT=128 nodes, 256 threads)
// ---------------------------------------------------------------------------
__global__ __launch_bounds__(256)
void build_bucket(const unsigned* __restrict__ epk, const int* __restrict__ histT,
                  const int* __restrict__ partials, int* __restrict__ offs,
                  float* __restrict__ invd, int* __restrict__ csr_src,
                  int nn, int E, int nbuk, int nba) {
    __shared__ int sm[BKT];
    __shared__ int cur[BKT];
    const int b   = blockIdx.x;
    const int b0  = b * BKT;
    const int tid = threadIdx.x;
    size_t i0 = (size_t)b * nba;
    const int ebase = histT[i0] + partials[i0 >> 8];
    int eend;
    if (b == nbuk - 1) eend = E;
    else {
        size_t i1 = (size_t)(b + 1) * nba;
        eend = histT[i1] + partials[i1 >> 8];
    }

    if (tid < BKT) sm[tid] = 0;
    __syncthreads();
    for (int j = ebase + tid; j < eend; j += 256)
        atomicAdd(&sm[epk[j] >> 17], 1);
    __syncthreads();
    const int deg = (tid < BKT) ? sm[tid] : 0;
    for (int d = 1; d < BKT; d <<= 1) {
        int t = (tid >= d && tid < BKT) ? sm[tid - d] : 0;
        __syncthreads();
        if (tid < BKT) sm[tid] += t;
        __syncthreads();
    }
    if (tid < BKT) {
        const int excl = sm[tid] - deg;
        const int n = b0 + tid;
        if (n < nn) {
            offs[n] = ebase + excl;
            invd[n] = 1.0f / fmaxf((float)deg, 1.0f);
        }
        if (b == nbuk - 1 && tid == 0) offs[nn] = E;
        cur[tid] = ebase + excl;
    }
    __syncthreads();
    for (int j = ebase + tid; j < eend; j += 256) {
        unsigned p = epk[j];
        int pos = atomicAdd(&cur[p >> 17], 1);
        csr_src[pos] = (int)(p & 0x1FFFFu);
    }
}

// ---------------------------------------------------------------------------
// fp8 edge-parallel gather, wave = node, 8B/lane, pipelined 4/2/1 ladder
// (next iteration's indices issued while current rows are in flight)
// ---------------------------------------------------------------------------
template<int D>
__global__ __launch_bounds__(256)
void gather_fp8(const uchar_t* __restrict__ xq, const int* __restrict__ csr_src,
                const int* __restrict__ offs, const float* __restrict__ invd,
                ushort_t* __restrict__ aggb, int nn) {
    constexpr int C  = D / 8;
    constexpr int NE = 64 / C;
    const int n = (blockIdx.x * 256 + threadIdx.x) >> 6;
    if (n >= nn) return;
    const int lane = threadIdx.x & 63;
    const int c  = lane % C;
    const int eg = lane / C;
    const uchar_t* tab = xq + (size_t)c * 8;

    const int beg = offs[n], end = offs[n + 1];
    f32x2 acc[4];
#pragma unroll
    for (int t = 0; t < 4; ++t) acc[t] = (f32x2){0.f, 0.f};

    int j = beg + eg;
    int i0, i1, i2, i3;
    bool have4 = (j + 3 * NE < end);
    if (have4) {
        i0 = csr_src[j];          i1 = csr_src[j + NE];
        i2 = csr_src[j + 2 * NE]; i3 = csr_src[j + 3 * NE];
    }
    while (have4) {
        uint2v q0 = *(const uint2v*)(tab + (size_t)i0 * D);
        uint2v q1 = *(const uint2v*)(tab + (size_t)i1 * D);
        uint2v q2 = *(const uint2v*)(tab + (size_t)i2 * D);
        uint2v q3 = *(const uint2v*)(tab + (size_t)i3 * D);
        j += 4 * NE;
        bool next4 = (j + 3 * NE < end);
        if (next4) {                           // overlap idx loads w/ row latency
            i0 = csr_src[j];          i1 = csr_src[j + NE];
            i2 = csr_src[j + 2 * NE]; i3 = csr_src[j + 3 * NE];
        }
#pragma unroll
        for (int d = 0; d < 2; ++d) {
            f32x2 l01 = fp8pair<false>(q0[d]) + fp8pair<false>(q1[d]);
            f32x2 l23 = fp8pair<false>(q2[d]) + fp8pair<false>(q3[d]);
            acc[2 * d] += l01 + l23;
            f32x2 h01 = fp8pair<true>(q0[d]) + fp8pair<true>(q1[d]);
            f32x2 h23 = fp8pair<true>(q2[d]) + fp8pair<true>(q3[d]);
            acc[2 * d + 1] += h01 + h23;
        }
        have4 = next4;
    }
    if (j + NE < end) {                       // 2-deep step
        int s0 = csr_src[j], s1 = csr_src[j + NE];
        uint2v q0 = *(const uint2v*)(tab + (size_t)s0 * D);
        uint2v q1 = *(const uint2v*)(tab + (size_t)s1 * D);
#pragma unroll
        for (int d = 0; d < 2; ++d) {
            acc[2 * d]     += fp8pair<false>(q0[d]) + fp8pair<false>(q1[d]);
            acc[2 * d + 1] += fp8pair<true>(q0[d]) + fp8pair<true>(q1[d]);
        }
        j += 2 * NE;
    }
    if (j < end) {                            // final single
        int s = csr_src[j];
        uint2v q = *(const uint2v*)(tab + (size_t)s * D);
#pragma unroll
        for (int d = 0; d < 2; ++d) {
            acc[2 * d]     += fp8pair<false>(q[d]);
            acc[2 * d + 1] += fp8pair<true>(q[d]);
        }
    }

    // reduce across edge groups (stride C within the wave)
#pragma unroll
    for (int m = C; m < 64; m <<= 1) {
#pragma unroll
        for (int t = 0; t < 4; ++t) {
            acc[t][0] += __shfl_xor(acc[t][0], m, 64);
            acc[t][1] += __shfl_xor(acc[t][1], m, 64);
        }
    }

    if (eg == 0) {
        float iv = invd[n];
        us8 ov;
#pragma unroll
        for (int t = 0; t < 4; ++t) {
            ov[2 * t]     = f2bf(acc[t][0] * iv);
            ov[2 * t + 1] = f2bf(acc[t][1] * iv);
        }
        *(us8*)(aggb + (size_t)n * D + c * 8) = ov;
    }
}

// ---------------------------------------------------------------------------
// Weight-stationary MFMA layer (layer 1): grid-stride over 64-node tiles
// ---------------------------------------------------------------------------
template<int K, int H, bool NEIGH, bool RELU, bool OBF, bool OFP8>
__global__ __launch_bounds__(256)
void mfma_layer(const ushort_t* __restrict__ xb, const ushort_t* __restrict__ gb,
                const ushort_t* __restrict__ wsT, const ushort_t* __restrict__ wnT,
                const float* __restrict__ bias, void* __restrict__ out,
                uchar_t* __restrict__ outq, int nn) {
    constexpr int CH   = K / 8;
    constexpr int KS   = K / 32;
    constexpr int WTPW = H / 64;
    constexpr int PF   = CH / 4;

    __shared__ us8 xs[64][CH];
    __shared__ us8 gs[NEIGH ? 64 : 1][NEIGH ? CH : 1];

    const int tid  = threadIdx.x;
    const int lane = tid & 63;
    const int w    = tid >> 6;
    const int lr   = lane & 15;
    const int lk   = lane >> 4;

    s16x8 bws[WTPW][KS];
    s16x8 bwn[NEIGH ? WTPW : 1][NEIGH ? KS : 1];
#pragma unroll
    for (int t = 0; t < WTPW; ++t) {
        const size_t hrow = (size_t)((w * WTPW + t) * 16 + lr) * K;
#pragma unroll
        for (int ks = 0; ks < KS; ++ks) {
            bws[t][ks] = *(const s16x8*)(wsT + hrow + ks * 32 + lk * 8);
            if constexpr (NEIGH)
                bwn[t][ks] = *(const s16x8*)(wnT + hrow + ks * 32 + lk * 8);
        }
    }
    float bv[WTPW];
#pragma unroll
    for (int t = 0; t < WTPW; ++t) bv[t] = bias[(w * WTPW + t) * 16 + lr];

    const int ntiles = (nn + 63) >> 6;
    us8 pfx[PF], pfg[NEIGH ? PF : 1];
    const us8 z8 = {0, 0, 0, 0, 0, 0, 0, 0};

    auto loadpf = [&](int T) {
        const int base = T * 64;
#pragma unroll
        for (int q = 0; q < PF; ++q) {
            int idx = tid + q * 256, r = idx / CH, c = idx % CH, n = base + r;
            pfx[q] = (n < nn) ? *(const us8*)(xb + (size_t)n * K + c * 8) : z8;
            if constexpr (NEIGH)
                pfg[q] = (n < nn) ? *(const us8*)(gb + (size_t)n * K + c * 8) : z8;
        }
    };

    int tile = blockIdx.x;
    if (tile >= ntiles) return;
    loadpf(tile);

    while (true) {
        __syncthreads();
#pragma unroll
        for (int q = 0; q < PF; ++q) {
            int idx = tid + q * 256, r = idx / CH, c = idx % CH;
            int cs = c ^ (r & 7);
            xs[r][cs] = pfx[q];
            if constexpr (NEIGH) gs[r][cs] = pfg[q];
        }
        __syncthreads();

        const int row0 = tile * 64;
        tile += gridDim.x;
        if (tile < ntiles) loadpf(tile);

        f32x4 acc[4][WTPW];
#pragma unroll
        for (int rg = 0; rg < 4; ++rg)
#pragma unroll
            for (int t = 0; t < WTPW; ++t) acc[rg][t] = {0.f, 0.f, 0.f, 0.f};

#pragma unroll
        for (int rg = 0; rg < 4; ++rg) {
            const int R = rg * 16 + lr;
#pragma unroll
            for (int ks = 0; ks < KS; ++ks) {
                const int cs = (ks * 4 + lk) ^ (R & 7);
                s16x8 ax = (s16x8)xs[R][cs];
                s16x8 ag;
                if constexpr (NEIGH) ag = (s16x8)gs[R][cs];
#pragma unroll
                for (int t = 0; t < WTPW; ++t) {
                    acc[rg][t] = __builtin_amdgcn_mfma_f32_16x16x32_bf16(ax, bws[t][ks], acc[rg][t], 0, 0, 0);
                    if constexpr (NEIGH)
                        acc[rg][t] = __builtin_amdgcn_mfma_f32_16x16x32_bf16(ag, bwn[t][ks], acc[rg][t], 0, 0, 0);
                }
            }
        }

#pragma unroll
        for (int rg = 0; rg < 4; ++rg) {
#pragma unroll
            for (int t = 0; t < WTPW; ++t) {
                const int h = (w * WTPW + t) * 16 + lr;
#pragma unroll
                for (int j = 0; j < 4; ++j) {
                    int n = row0 + rg * 16 + lk * 4 + j;
                    if (n < nn) {
                        float v = acc[rg][t][j] + bv[t];
                        if constexpr (RELU) v = fmaxf(v, 0.f);
                        if constexpr (OBF)
                            ((ushort_t*)out)[(size_t)n * H + h] = f2bf(v);
                        else
                            ((float*)out)[(size_t)n * H + h] = v;
                        if constexpr (OFP8)
                            outq[(size_t)n * H + h] = f2fp8(v);
                    }
                }
            }
        }

        if (tile >= ntiles) break;
    }
}

// ---------------------------------------------------------------------------
// Fused tail: x2 = relu(x1@Ws2 + agg2@Wn2 + b2); x3 = relu(x2@Wm1 + bm1);
//             out = x3@Wm2 + bm2
// ---------------------------------------------------------------------------
__global__ __launch_bounds__(256)
void mfma_tail(const ushort_t* __restrict__ xb, const ushort_t* __restrict__ gb,
               const ushort_t* __restrict__ wsT2, const ushort_t* __restrict__ wnT2,
               const ushort_t* __restrict__ wmT1, const ushort_t* __restrict__ wmT2,
               const float* __restrict__ b2, const float* __restrict__ bm1,
               const float* __restrict__ bm2, float* __restrict__ out, int nn) {
    constexpr int CH = 16, KS = 4, PF = 4;
    __shared__ us8 xs[64][CH];
    __shared__ us8 gs[64][CH];
    ushort_t* xs16 = (ushort_t*)xs;
    ushort_t* gs16 = (ushort_t*)gs;

    const int tid  = threadIdx.x;
    const int lane = tid & 63;
    const int w    = tid >> 6;
    const int lr   = lane & 15;
    const int lk   = lane >> 4;

    s16x8 bws2[2][KS], bwn2[2][KS], bwm1[2][KS], bwm2[KS];
#pragma unroll
    for (int t = 0; t < 2; ++t) {
        const size_t hrow = (size_t)((w * 2 + t) * 16 + lr) * HID;
#pragma unroll
        for (int ks = 0; ks < KS; ++ks) {
            bws2[t][ks] = *(const s16x8*)(wsT2 + hrow + ks * 32 + lk * 8);
            bwn2[t][ks] = *(const s16x8*)(wnT2 + hrow + ks * 32 + lk * 8);
            bwm1[t][ks] = *(const s16x8*)(wmT1 + hrow + ks * 32 + lk * 8);
        }
    }
    {
        const size_t hrow = (size_t)(w * 16 + lr) * HID;
#pragma unroll
        for (int ks = 0; ks < KS; ++ks)
            bwm2[ks] = *(const s16x8*)(wmT2 + hrow + ks * 32 + lk * 8);
    }
    float bv2[2]  = {b2[(w * 2) * 16 + lr],  b2[(w * 2 + 1) * 16 + lr]};
    float bvm1[2] = {bm1[(w * 2) * 16 + lr], bm1[(w * 2 + 1) * 16 + lr]};
    float bvm2    = bm2[w * 16 + lr];

    const int ntiles = (nn + 63) >> 6;
    us8 pfx[PF], pfg[PF];
    const us8 z8 = {0, 0, 0, 0, 0, 0, 0, 0};

    auto loadpf = [&](int T) {
        const int base = T * 64;
#pragma unroll
        for (int q = 0; q < PF; ++q) {
            int idx = tid + q * 256, r = idx / CH, c = idx % CH, n = base + r;
            pfx[q] = (n < nn) ? *(const us8*)(xb + (size_t)n * HID + c * 8) : z8;
            pfg[q] = (n < nn) ? *(const us8*)(gb + (size_t)n * HID + c * 8) : z8;
        }
    };

    auto st_bf = [&](ushort_t* base, int r, int h, float v) {
        int c8 = h >> 3, e = h & 7;
        int cs = c8 ^ (r & 7);
        base[r * 128 + cs * 8 + e] = f2bf(v);
    };

    int tile = blockIdx.x;
    if (tile >= ntiles) return;
    loadpf(tile);

    while (true) {
        __syncthreads();
#pragma unroll
        for (int q = 0; q < PF; ++q) {
            int idx = tid + q * 256, r = idx / CH, c = idx % CH;
            int cs = c ^ (r & 7);
            xs[r][cs] = pfx[q];
            gs[r][cs] = pfg[q];
        }
        __syncthreads();

        const int row0 = tile * 64;
        tile += gridDim.x;
        if (tile < ntiles) loadpf(tile);

        // ---- stage 1: x2 = relu(x1@Ws2 + agg2@Wn2 + b2) ----
        f32x4 a1[4][2];
#pragma unroll
        for (int rg = 0; rg < 4; ++rg)
#pragma unroll
            for (int t = 0; t < 2; ++t) a1[rg][t] = {0.f, 0.f, 0.f, 0.f};
#pragma unroll
        for (int rg = 0; rg < 4; ++rg) {
            const int R = rg * 16 + lr;
#pragma unroll
            for (int ks = 0; ks < KS; ++ks) {
                const int cs = (ks * 4 + lk) ^ (R & 7);
                s16x8 ax = (s16x8)xs[R][cs];
                s16x8 ag = (s16x8)gs[R][cs];
#pragma unroll
                for (int t = 0; t < 2; ++t) {
                    a1[rg][t] = __builtin_amdgcn_mfma_f32_16x16x32_bf16(ax, bws2[t][ks], a1[rg][t], 0, 0, 0);
                    a1[rg][t] = __builtin_amdgcn_mfma_f32_16x16x32_bf16(ag, bwn2[t][ks], a1[rg][t], 0, 0, 0);
                }
            }
        }
        __syncthreads();
#pragma unroll
        for (int rg = 0; rg < 4; ++rg)
#pragma unroll
            for (int t = 0; t < 2; ++t) {
                const int h = (w * 2 + t) * 16 + lr;
#pragma unroll
                for (int j = 0; j < 4; ++j) {
                    int r = rg * 16 + lk * 4 + j;
                    st_bf(gs16, r, h, fmaxf(a1[rg][t][j] + bv2[t], 0.f));
                }
            }
        __syncthreads();

        // ---- stage 2: x3 = relu(x2@Wm1 + bm1) ----
        f32x4 a2[4][2];
#pragma unroll
        for (int rg = 0; rg < 4; ++rg)
#pragma unroll
            for (int t = 0; t < 2; ++t) a2[rg][t] = {0.f, 0.f, 0.f, 0.f};
#pragma unroll
        for (int rg = 0; rg < 4; ++rg) {
            const int R = rg * 16 + lr;
#pragma unroll
            for (int ks = 0; ks < KS; ++ks) {
                const int cs = (ks * 4 + lk) ^ (R & 7);
                s16x8 ax = (s16x8)gs[R][cs];
#pragma unroll
                for (int t = 0; t < 2; ++t)
                    a2[rg][t] = __builtin_amdgcn_mfma_f32_16x16x32_bf16(ax, bwm1[t][ks], a2[rg][t], 0, 0, 0);
            }
        }
        __syncthreads();
#pragma unroll
        for (int rg = 0; rg < 4; ++rg)
#pragma unroll
            for (int t = 0; t < 2; ++t) {
                const int h = (w * 2 + t) * 16 + lr;
#pragma unroll
                for (int j = 0; j < 4; ++j) {
                    int r = rg * 16 + lk * 4 + j;
                    st_bf(xs16, r, h, fmaxf(a2[rg][t][j] + bvm1[t], 0.f));
                }
            }
        __syncthreads();

        // ---- stage 3: out = x3@Wm2 + bm2 (fp32, H=64) ----
        f32x4 a3[4];
#pragma unroll
        for (int rg = 0; rg < 4; ++rg) a3[rg] = {0.f, 0.f, 0.f, 0.f};
#pragma unroll
        for (int rg = 0; rg < 4; ++rg) {
            const int R = rg * 16 + lr;
#pragma unroll
            for (int ks = 0; ks < KS; ++ks) {
                const int cs = (ks * 4 + lk) ^ (R & 7);
                s16x8 ax = (s16x8)xs[R][cs];
                a3[rg] = __builtin_amdgcn_mfma_f32_16x16x32_bf16(ax, bwm2[ks], a3[rg], 0, 0, 0);
            }
        }
        const int h3 = w * 16 + lr;
#pragma unroll
        for (int rg = 0; rg < 4; ++rg)
#pragma unroll
            for (int j = 0; j < 4; ++j) {
                int n = row0 + rg * 16 + lk * 4 + j;
                if (n < nn) out[(size_t)n * OUT_F + h3] = a3[rg][j] + bvm2;
            }

        if (tile >= ntiles) break;
    }
}

// ---------------------------------------------------------------------------
extern "C" void kernel_launch(void* const* d_in, const int* in_sizes, int n_in,
                              void* d_out, int out_size, void* d_ws, size_t ws_size,
                              hipStream_t stream) {
    const float* feat = (const float*)d_in[0];
    const float* Wn1  = (const float*)d_in[1];
    const float* Ws1  = (const float*)d_in[2];
    const float* b1   = (const float*)d_in[3];
    const float* Wn2  = (const float*)d_in[4];
    const float* Ws2  = (const float*)d_in[5];
    const float* b2   = (const float*)d_in[6];
    const float* Wm1  = (const float*)d_in[7];
    const float* bm1  = (const float*)d_in[8];
    const float* Wm2  = (const float*)d_in[9];
    const float* bm2  = (const float*)d_in[10];
    const int*   src  = (const int*)d_in[11];
    const int*   dst  = (const int*)d_in[12];

    const int nn = in_sizes[0] / N_IN;    // 100000 (< 2^17, required by pack)
    const int E  = in_sizes[11];          // 1600000

    const int nbuk  = (nn + BKT - 1) / BKT;   // 782 buckets
    const int nba   = (E + EPB - 1) / EPB;    // 131 partition blocks
    const int nhist = nbuk * nba;             // ~102K

    // ---- workspace carve-up (64B-aligned) ----
    char* p = (char*)d_ws;
    auto alloc = [&](size_t bytes) { void* q = p; p += (bytes + 63) & ~(size_t)63; return q; };
    int*      offs     = (int*)alloc((size_t)(nn + 1) * 4);
    int*      partials = (int*)alloc(1024 * 4);
    float*    invd     = (float*)alloc((size_t)nn * 4);
    int*      histT    = (int*)alloc((size_t)nhist * 4);
    unsigned* epk      = (unsigned*)alloc((size_t)E * 4);
    int*      csr_src  = (int*)alloc((size_t)E * 4);
    ushort_t* wsT1     = (ushort_t*)alloc((size_t)N_IN * HID * 2);
    ushort_t* wnT1     = (ushort_t*)alloc((size_t)N_IN * HID * 2);
    ushort_t* wsT2     = (ushort_t*)alloc((size_t)HID * HID * 2);
    ushort_t* wnT2     = (ushort_t*)alloc((size_t)HID * HID * 2);
    ushort_t* wmT1     = (ushort_t*)alloc((size_t)HID * HID * 2);
    ushort_t* wmT2     = (ushort_t*)alloc((size_t)HID * OUT_F * 2);
    ushort_t* featb    = (ushort_t*)alloc((size_t)nn * N_IN * 2);
    uchar_t*  x1q      = (uchar_t*)alloc((size_t)nn * HID);
    ushort_t* x1b      = (ushort_t*)alloc((size_t)nn * HID * 2);
    ushort_t* agg2b    = (ushort_t*)alloc((size_t)nn * HID * 2);
    ushort_t* agg1b    = (ushort_t*)d_out;            // dead after mfma_layer1
    uchar_t*  featq    = (uchar_t*)d_out + (size_t)nn * N_IN * 2;
    // agg1b/featq occupy d_out only until mfma_layer1 completes; tail writes
    // d_out afterwards (same stream, ordered).

    const int ntiles = (nn + 63) / 64;
    const int NB     = ntiles < 768 ? ntiles : 768;
    const int NBT    = ntiles < 512 ? ntiles : 512;
    const int n8     = nn * (N_IN / 8);
    const int BA     = (n8 + 255) / 256;
    const int BB     = BA + (73728 + 255) / 256;
    const int BC     = BB + nba;

    // ---- fused prep: conversions + bucket histograms ----
    prep_kernel<<<BC, 256, 0, stream>>>(
        feat, featb, featq, n8,
        Ws1, Wn1, Ws2, Wn2, Wm1, Wm2,
        wsT1, wnT1, wsT2, wnT2, wmT1, wmT2,
        dst, histT, E, nbuk, nba, BA, BB);

    // ---- scan histT (scan_add folded into consumers) ----
    const int nparts = (nhist + 255) / 256;           // ~401 <= 1024
    scan_block<<<nparts, 256, 0, stream>>>(histT, histT, partials, nhist);
    scan_partials<<<1, 1024, 0, stream>>>(partials, nparts);

    // ---- partition + per-bucket CSR build ----
    part_edges<<<nba, 256, 0, stream>>>(src, dst, histT, partials, epk, E, nbuk, nba);
    build_bucket<<<nbuk, 256, 0, stream>>>(epk, histT, partials, offs, invd, csr_src, nn, E, nbuk, nba);

    // ---- layer 1 ----
    gather_fp8<N_IN><<<(nn + 3) / 4, 256, 0, stream>>>(
        featq, csr_src, offs, invd, agg1b, nn);
    mfma_layer<N_IN, HID, true, true, true, true><<<NB, 256, 0, stream>>>(
        featb, agg1b, wsT1, wnT1, b1, x1b, x1q, nn);

    // ---- layer 2 gather ----
    gather_fp8<HID><<<(nn + 3) / 4, 256, 0, stream>>>(
        x1q, csr_src, offs, invd, agg2b, nn);

    // ---- fused tail: SAGE-2 + MLP1 + MLP2 -> d_out ----
    mfma_tail<<<NBT, 256, 0, stream>>>(
        x1b, agg2b, wsT2, wnT2, wmT1, wmT2, b2, bm1, bm2, (float*)d_out, nn);
}

// Round 16
// 198.383 us; speedup vs baseline: 1.0556x; 1.0556x over previous
//
#include <hip/hip_runtime.h>
#include <hip/hip_fp8.h>

#define N_IN 64
#define HID 128
#define OUT_F 64
#define EPB 6144          // edges per partition block (24 iters x 256)
#define BKT 128           // nodes per bucket (pow2; dlocal fits 7 bits)

typedef unsigned short ushort_t;
typedef unsigned char  uchar_t;
typedef ushort_t us8  __attribute__((ext_vector_type(8)));
typedef uchar_t  uc8  __attribute__((ext_vector_type(8)));
typedef short    s16x8 __attribute__((ext_vector_type(8)));
typedef float    f32x4 __attribute__((ext_vector_type(4)));
typedef float    f32x2 __attribute__((ext_vector_type(2)));
typedef unsigned int uint2v __attribute__((ext_vector_type(2)));

__device__ inline ushort_t f2bf(float f) {          // round-to-nearest-even
    unsigned u = __float_as_uint(f);
    u = u + 0x7fffu + ((u >> 16) & 1u);
    return (ushort_t)(u >> 16);
}
__device__ inline float bf2f(ushort_t b) {
    return __uint_as_float((unsigned)b << 16);
}
__device__ inline uchar_t f2fp8(float v) {          // OCP e4m3
    __hip_fp8_e4m3 q(v);
    return (uchar_t)q.__x;
}
template<bool HI>
__device__ inline f32x2 fp8pair(unsigned int dw) {
#if __has_builtin(__builtin_amdgcn_cvt_pk_f32_fp8)
    auto r = __builtin_amdgcn_cvt_pk_f32_fp8(dw, HI);   // HI is a literal
    f32x2 o; o[0] = r[0]; o[1] = r[1];
    return o;
#else
    f32x2 o;
#pragma unroll
    for (int i = 0; i < 2; ++i) {
        __hip_fp8_e4m3 h; h.__x = (dw >> (8 * (2 * (int)HI + i))) & 0xff;
        o[i] = (float)h;
    }
    return o;
#endif
}

// ---------------------------------------------------------------------------
// fused prep:
//   [0,BA)   feat fp32 -> bf16 + fp8
//   [BA,BB)  weights -> bf16 transposed
//   [BB,BC)  pass A: per-block bucket histogram (LDS atomics only)
// ---------------------------------------------------------------------------
__global__ __launch_bounds__(256)
void prep_kernel(const float* __restrict__ feat, ushort_t* __restrict__ featb,
                 uchar_t* __restrict__ featq, int n8,
                 const float* __restrict__ Ws1, const float* __restrict__ Wn1,
                 const float* __restrict__ Ws2, const float* __restrict__ Wn2,
                 const float* __restrict__ Wm1, const float* __restrict__ Wm2,
                 ushort_t* __restrict__ wsT1, ushort_t* __restrict__ wnT1,
                 ushort_t* __restrict__ wsT2, ushort_t* __restrict__ wnT2,
                 ushort_t* __restrict__ wmT1, ushort_t* __restrict__ wmT2,
                 const int* __restrict__ dst, int* __restrict__ histT,
                 int E, int nbuk, int nba, int BA, int BB) {
    __shared__ int hist[800];
    int b = blockIdx.x;
    int tid = threadIdx.x;
    if (b < BA) {
        int i = b * 256 + tid;
        if (i >= n8) return;
        f32x4 a = ((const f32x4*)feat)[2 * i];
        f32x4 c = ((const f32x4*)feat)[2 * i + 1];
        us8 v; uc8 q;
#pragma unroll
        for (int t = 0; t < 4; ++t) {
            v[t] = f2bf(a[t]); v[4 + t] = f2bf(c[t]);
            q[t] = f2fp8(a[t]); q[4 + t] = f2fp8(c[t]);
        }
        ((us8*)featb)[i] = v;
        ((uc8*)featq)[i] = q;
    } else if (b < BB) {
        int i = (b - BA) * 256 + tid;
        const float* W; ushort_t* WT; int K, H, l;
        if      (i < 8192)  { W = Ws1; WT = wsT1; K = 64;  H = 128; l = i; }
        else if (i < 16384) { W = Wn1; WT = wnT1; K = 64;  H = 128; l = i - 8192; }
        else if (i < 32768) { W = Ws2; WT = wsT2; K = 128; H = 128; l = i - 16384; }
        else if (i < 49152) { W = Wn2; WT = wnT2; K = 128; H = 128; l = i - 32768; }
        else if (i < 65536) { W = Wm1; WT = wmT1; K = 128; H = 128; l = i - 49152; }
        else if (i < 73728) { W = Wm2; WT = wmT2; K = 128; H = 64;  l = i - 65536; }
        else return;
        int h = l / K, k = l % K;
        WT[l] = f2bf(W[(size_t)k * H + h]);
    } else {
        const int blk  = b - BB;
        const int base = blk * EPB;
        for (int k = tid; k < nbuk; k += 256) hist[k] = 0;
        __syncthreads();
#pragma unroll 4
        for (int it = 0; it < EPB / 256; ++it) {
            int e = base + it * 256 + tid;
            if (e < E) atomicAdd(&hist[(unsigned)dst[e] / BKT], 1);
        }
        __syncthreads();
        for (int k = tid; k < nbuk; k += 256)
            histT[(size_t)k * nba + blk] = hist[k];
    }
}

// ---------------------------------------------------------------------------
// scan (2 kernels): per-256 block exclusive scan; partials exclusive scan.
// consumers add partials[idx>>8] themselves (scan_add folded away).
// ---------------------------------------------------------------------------
__global__ __launch_bounds__(256)
void scan_block(const int* __restrict__ in, int* __restrict__ out,
                int* __restrict__ partials, int n) {
    __shared__ int sm[256];
    int i = blockIdx.x * 256 + threadIdx.x;
    int v = (i < n) ? in[i] : 0;
    sm[threadIdx.x] = v;
    __syncthreads();
    for (int d = 1; d < 256; d <<= 1) {
        int t = (threadIdx.x >= d) ? sm[threadIdx.x - d] : 0;
        __syncthreads();
        sm[threadIdx.x] += t;
        __syncthreads();
    }
    if (i < n) out[i] = sm[threadIdx.x] - v;
    if (threadIdx.x == 255) partials[blockIdx.x] = sm[255];
}

__global__ __launch_bounds__(1024)
void scan_partials(int* __restrict__ partials, int nparts) {
    __shared__ int sm[1024];
    int i = threadIdx.x;
    int v = (i < nparts) ? partials[i] : 0;
    sm[i] = v;
    __syncthreads();
    for (int d = 1; d < 1024; d <<= 1) {
        int t = (i >= d) ? sm[i - d] : 0;
        __syncthreads();
        sm[i] += t;
        __syncthreads();
    }
    if (i < nparts) partials[i] = sm[i] - v;
}

// ---------------------------------------------------------------------------
// pass C: bucket-partition edges; u32-packed (dlocal<<17 | src); LDS cursors
// ---------------------------------------------------------------------------
__global__ __launch_bounds__(256)
void part_edges(const int* __restrict__ src, const int* __restrict__ dst,
                const int* __restrict__ histT, const int* __restrict__ partials,
                unsigned* __restrict__ epk, int E, int nbuk, int nba) {
    __shared__ int cur[800];
    const int blk  = blockIdx.x;
    const int base = blk * EPB;
    const int tid  = threadIdx.x;
    for (int k = tid; k < nbuk; k += 256) {
        size_t idx = (size_t)k * nba + blk;
        cur[k] = histT[idx] + partials[idx >> 8];
    }
    __syncthreads();
#pragma unroll 4
    for (int it = 0; it < EPB / 256; ++it) {
        int e = base + it * 256 + tid;
        if (e < E) {
            unsigned d = (unsigned)dst[e], s = (unsigned)src[e];
            int pos = atomicAdd(&cur[d / BKT], 1);
            epk[pos] = ((d & (BKT - 1)) << 17) | s;     // nn < 2^17
        }
    }
}

// ---------------------------------------------------------------------------
// pass D: per-bucket CSR finalize (BKT=128 nodes, 256 threads)
// ---------------------------------------------------------------------------
__global__ __launch_bounds__(256)
void build_bucket(const unsigned* __restrict__ epk, const int* __restrict__ histT,
                  const int* __restrict__ partials, int* __restrict__ offs,
                  float* __restrict__ invd, int* __restrict__ csr_src,
                  int nn, int E, int nbuk, int nba) {
    __shared__ int sm[BKT];
    __shared__ int cur[BKT];
    const int b   = blockIdx.x;
    const int b0  = b * BKT;
    const int tid = threadIdx.x;
    size_t i0 = (size_t)b * nba;
    const int ebase = histT[i0] + partials[i0 >> 8];
    int eend;
    if (b == nbuk - 1) eend = E;
    else {
        size_t i1 = (size_t)(b + 1) * nba;
        eend = histT[i1] + partials[i1 >> 8];
    }

    if (tid < BKT) sm[tid] = 0;
    __syncthreads();
    for (int j = ebase + tid; j < eend; j += 256)
        atomicAdd(&sm[epk[j] >> 17], 1);
    __syncthreads();
    const int deg = (tid < BKT) ? sm[tid] : 0;
    for (int d = 1; d < BKT; d <<= 1) {
        int t = (tid >= d && tid < BKT) ? sm[tid - d] : 0;
        __syncthreads();
        if (tid < BKT) sm[tid] += t;
        __syncthreads();
    }
    if (tid < BKT) {
        const int excl = sm[tid] - deg;
        const int n = b0 + tid;
        if (n < nn) {
            offs[n] = ebase + excl;
            invd[n] = 1.0f / fmaxf((float)deg, 1.0f);
        }
        if (b == nbuk - 1 && tid == 0) offs[nn] = E;
        cur[tid] = ebase + excl;
    }
    __syncthreads();
    for (int j = ebase + tid; j < eend; j += 256) {
        unsigned p = epk[j];
        int pos = atomicAdd(&cur[p >> 17], 1);
        csr_src[pos] = (int)(p & 0x1FFFFu);
    }
}

// ---------------------------------------------------------------------------
// fp8 edge-parallel gather, wave = node, 8B/lane, pipelined 4/2/1 ladder
// ---------------------------------------------------------------------------
template<int D>
__global__ __launch_bounds__(256)
void gather_fp8(const uchar_t* __restrict__ xq, const int* __restrict__ csr_src,
                const int* __restrict__ offs, const float* __restrict__ invd,
                ushort_t* __restrict__ aggb, int nn) {
    constexpr int C  = D / 8;
    constexpr int NE = 64 / C;
    const int n = (blockIdx.x * 256 + threadIdx.x) >> 6;
    if (n >= nn) return;
    const int lane = threadIdx.x & 63;
    const int c  = lane % C;
    const int eg = lane / C;
    const uchar_t* tab = xq + (size_t)c * 8;

    const int beg = offs[n], end = offs[n + 1];
    f32x2 acc[4];
#pragma unroll
    for (int t = 0; t < 4; ++t) acc[t] = (f32x2){0.f, 0.f};

    int j = beg + eg;
    int i0, i1, i2, i3;
    bool have4 = (j + 3 * NE < end);
    if (have4) {
        i0 = csr_src[j];          i1 = csr_src[j + NE];
        i2 = csr_src[j + 2 * NE]; i3 = csr_src[j + 3 * NE];
    }
    while (have4) {
        uint2v q0 = *(const uint2v*)(tab + (size_t)i0 * D);
        uint2v q1 = *(const uint2v*)(tab + (size_t)i1 * D);
        uint2v q2 = *(const uint2v*)(tab + (size_t)i2 * D);
        uint2v q3 = *(const uint2v*)(tab + (size_t)i3 * D);
        j += 4 * NE;
        bool next4 = (j + 3 * NE < end);
        if (next4) {                           // overlap idx loads w/ row latency
            i0 = csr_src[j];          i1 = csr_src[j + NE];
            i2 = csr_src[j + 2 * NE]; i3 = csr_src[j + 3 * NE];
        }
#pragma unroll
        for (int d = 0; d < 2; ++d) {
            f32x2 l01 = fp8pair<false>(q0[d]) + fp8pair<false>(q1[d]);
            f32x2 l23 = fp8pair<false>(q2[d]) + fp8pair<false>(q3[d]);
            acc[2 * d] += l01 + l23;
            f32x2 h01 = fp8pair<true>(q0[d]) + fp8pair<true>(q1[d]);
            f32x2 h23 = fp8pair<true>(q2[d]) + fp8pair<true>(q3[d]);
            acc[2 * d + 1] += h01 + h23;
        }
        have4 = next4;
    }
    if (j + NE < end) {                       // 2-deep step
        int s0 = csr_src[j], s1 = csr_src[j + NE];
        uint2v q0 = *(const uint2v*)(tab + (size_t)s0 * D);
        uint2v q1 = *(const uint2v*)(tab + (size_t)s1 * D);
#pragma unroll
        for (int d = 0; d < 2; ++d) {
            acc[2 * d]     += fp8pair<false>(q0[d]) + fp8pair<false>(q1[d]);
            acc[2 * d + 1] += fp8pair<true>(q0[d]) + fp8pair<true>(q1[d]);
        }
        j += 2 * NE;
    }
    if (j < end) {                            // final single
        int s = csr_src[j];
        uint2v q = *(const uint2v*)(tab + (size_t)s * D);
#pragma unroll
        for (int d = 0; d < 2; ++d) {
            acc[2 * d]     += fp8pair<false>(q[d]);
            acc[2 * d + 1] += fp8pair<true>(q[d]);
        }
    }

    // reduce across edge groups (stride C within the wave)
#pragma unroll
    for (int m = C; m < 64; m <<= 1) {
#pragma unroll
        for (int t = 0; t < 4; ++t) {
            acc[t][0] += __shfl_xor(acc[t][0], m, 64);
            acc[t][1] += __shfl_xor(acc[t][1], m, 64);
        }
    }

    if (eg == 0) {
        float iv = invd[n];
        us8 ov;
#pragma unroll
        for (int t = 0; t < 4; ++t) {
            ov[2 * t]     = f2bf(acc[t][0] * iv);
            ov[2 * t + 1] = f2bf(acc[t][1] * iv);
        }
        *(us8*)(aggb + (size_t)n * D + c * 8) = ov;
    }
}

// ---------------------------------------------------------------------------
// Weight-stationary MFMA layer (layer 1): grid-stride over 64-node tiles
// ---------------------------------------------------------------------------
template<int K, int H, bool NEIGH, bool RELU, bool OBF, bool OFP8>
__global__ __launch_bounds__(256)
void mfma_layer(const ushort_t* __restrict__ xb, const ushort_t* __restrict__ gb,
                const ushort_t* __restrict__ wsT, const ushort_t* __restrict__ wnT,
                const float* __restrict__ bias, void* __restrict__ out,
                uchar_t* __restrict__ outq, int nn) {
    constexpr int CH   = K / 8;
    constexpr int KS   = K / 32;
    constexpr int WTPW = H / 64;
    constexpr int PF   = CH / 4;

    __shared__ us8 xs[64][CH];
    __shared__ us8 gs[NEIGH ? 64 : 1][NEIGH ? CH : 1];

    const int tid  = threadIdx.x;
    const int lane = tid & 63;
    const int w    = tid >> 6;
    const int lr   = lane & 15;
    const int lk   = lane >> 4;

    s16x8 bws[WTPW][KS];
    s16x8 bwn[NEIGH ? WTPW : 1][NEIGH ? KS : 1];
#pragma unroll
    for (int t = 0; t < WTPW; ++t) {
        const size_t hrow = (size_t)((w * WTPW + t) * 16 + lr) * K;
#pragma unroll
        for (int ks = 0; ks < KS; ++ks) {
            bws[t][ks] = *(const s16x8*)(wsT + hrow + ks * 32 + lk * 8);
            if constexpr (NEIGH)
                bwn[t][ks] = *(const s16x8*)(wnT + hrow + ks * 32 + lk * 8);
        }
    }
    float bv[WTPW];
#pragma unroll
    for (int t = 0; t < WTPW; ++t) bv[t] = bias[(w * WTPW + t) * 16 + lr];

    const int ntiles = (nn + 63) >> 6;
    us8 pfx[PF], pfg[NEIGH ? PF : 1];
    const us8 z8 = {0, 0, 0, 0, 0, 0, 0, 0};

    auto loadpf = [&](int T) {
        const int base = T * 64;
#pragma unroll
        for (int q = 0; q < PF; ++q) {
            int idx = tid + q * 256, r = idx / CH, c = idx % CH, n = base + r;
            pfx[q] = (n < nn) ? *(const us8*)(xb + (size_t)n * K + c * 8) : z8;
            if constexpr (NEIGH)
                pfg[q] = (n < nn) ? *(const us8*)(gb + (size_t)n * K + c * 8) : z8;
        }
    };

    int tile = blockIdx.x;
    if (tile >= ntiles) return;
    loadpf(tile);

    while (true) {
        __syncthreads();
#pragma unroll
        for (int q = 0; q < PF; ++q) {
            int idx = tid + q * 256, r = idx / CH, c = idx % CH;
            int cs = c ^ (r & 7);
            xs[r][cs] = pfx[q];
            if constexpr (NEIGH) gs[r][cs] = pfg[q];
        }
        __syncthreads();

        const int row0 = tile * 64;
        tile += gridDim.x;
        if (tile < ntiles) loadpf(tile);

        f32x4 acc[4][WTPW];
#pragma unroll
        for (int rg = 0; rg < 4; ++rg)
#pragma unroll
            for (int t = 0; t < WTPW; ++t) acc[rg][t] = {0.f, 0.f, 0.f, 0.f};

#pragma unroll
        for (int rg = 0; rg < 4; ++rg) {
            const int R = rg * 16 + lr;
#pragma unroll
            for (int ks = 0; ks < KS; ++ks) {
                const int cs = (ks * 4 + lk) ^ (R & 7);
                s16x8 ax = (s16x8)xs[R][cs];
                s16x8 ag;
                if constexpr (NEIGH) ag = (s16x8)gs[R][cs];
#pragma unroll
                for (int t = 0; t < WTPW; ++t) {
                    acc[rg][t] = __builtin_amdgcn_mfma_f32_16x16x32_bf16(ax, bws[t][ks], acc[rg][t], 0, 0, 0);
                    if constexpr (NEIGH)
                        acc[rg][t] = __builtin_amdgcn_mfma_f32_16x16x32_bf16(ag, bwn[t][ks], acc[rg][t], 0, 0, 0);
                }
            }
        }

#pragma unroll
        for (int rg = 0; rg < 4; ++rg) {
#pragma unroll
            for (int t = 0; t < WTPW; ++t) {
                const int h = (w * WTPW + t) * 16 + lr;
#pragma unroll
                for (int j = 0; j < 4; ++j) {
                    int n = row0 + rg * 16 + lk * 4 + j;
                    if (n < nn) {
                        float v = acc[rg][t][j] + bv[t];
                        if constexpr (RELU) v = fmaxf(v, 0.f);
                        if constexpr (OBF)
                            ((ushort_t*)out)[(size_t)n * H + h] = f2bf(v);
                        else
                            ((float*)out)[(size_t)n * H + h] = v;
                        if constexpr (OFP8)
                            outq[(size_t)n * H + h] = f2fp8(v);
                    }
                }
            }
        }

        if (tile >= ntiles) break;
    }
}

// ---------------------------------------------------------------------------
// Fused tail: x2 = relu(x1@Ws2 + agg2@Wn2 + b2); x3 = relu(x2@Wm1 + bm1);
//             out = x3@Wm2 + bm2
// ---------------------------------------------------------------------------
__global__ __launch_bounds__(256)
void mfma_tail(const ushort_t* __restrict__ xb, const ushort_t* __restrict__ gb,
               const ushort_t* __restrict__ wsT2, const ushort_t* __restrict__ wnT2,
               const ushort_t* __restrict__ wmT1, const ushort_t* __restrict__ wmT2,
               const float* __restrict__ b2, const float* __restrict__ bm1,
               const float* __restrict__ bm2, float* __restrict__ out, int nn) {
    constexpr int CH = 16, KS = 4, PF = 4;
    __shared__ us8 xs[64][CH];
    __shared__ us8 gs[64][CH];
    ushort_t* xs16 = (ushort_t*)xs;
    ushort_t* gs16 = (ushort_t*)gs;

    const int tid  = threadIdx.x;
    const int lane = tid & 63;
    const int w    = tid >> 6;
    const int lr   = lane & 15;
    const int lk   = lane >> 4;

    s16x8 bws2[2][KS], bwn2[2][KS], bwm1[2][KS], bwm2[KS];
#pragma unroll
    for (int t = 0; t < 2; ++t) {
        const size_t hrow = (size_t)((w * 2 + t) * 16 + lr) * HID;
#pragma unroll
        for (int ks = 0; ks < KS; ++ks) {
            bws2[t][ks] = *(const s16x8*)(wsT2 + hrow + ks * 32 + lk * 8);
            bwn2[t][ks] = *(const s16x8*)(wnT2 + hrow + ks * 32 + lk * 8);
            bwm1[t][ks] = *(const s16x8*)(wmT1 + hrow + ks * 32 + lk * 8);
        }
    }
    {
        const size_t hrow = (size_t)(w * 16 + lr) * HID;
#pragma unroll
        for (int ks = 0; ks < KS; ++ks)
            bwm2[ks] = *(const s16x8*)(wmT2 + hrow + ks * 32 + lk * 8);
    }
    float bv2[2]  = {b2[(w * 2) * 16 + lr],  b2[(w * 2 + 1) * 16 + lr]};
    float bvm1[2] = {bm1[(w * 2) * 16 + lr], bm1[(w * 2 + 1) * 16 + lr]};
    float bvm2    = bm2[w * 16 + lr];

    const int ntiles = (nn + 63) >> 6;
    us8 pfx[PF], pfg[PF];
    const us8 z8 = {0, 0, 0, 0, 0, 0, 0, 0};

    auto loadpf = [&](int T) {
        const int base = T * 64;
#pragma unroll
        for (int q = 0; q < PF; ++q) {
            int idx = tid + q * 256, r = idx / CH, c = idx % CH, n = base + r;
            pfx[q] = (n < nn) ? *(const us8*)(xb + (size_t)n * HID + c * 8) : z8;
            pfg[q] = (n < nn) ? *(const us8*)(gb + (size_t)n * HID + c * 8) : z8;
        }
    };

    auto st_bf = [&](ushort_t* base, int r, int h, float v) {
        int c8 = h >> 3, e = h & 7;
        int cs = c8 ^ (r & 7);
        base[r * 128 + cs * 8 + e] = f2bf(v);
    };

    int tile = blockIdx.x;
    if (tile >= ntiles) return;
    loadpf(tile);

    while (true) {
        __syncthreads();
#pragma unroll
        for (int q = 0; q < PF; ++q) {
            int idx = tid + q * 256, r = idx / CH, c = idx % CH;
            int cs = c ^ (r & 7);
            xs[r][cs] = pfx[q];
            gs[r][cs] = pfg[q];
        }
        __syncthreads();

        const int row0 = tile * 64;
        tile += gridDim.x;
        if (tile < ntiles) loadpf(tile);

        // ---- stage 1: x2 = relu(x1@Ws2 + agg2@Wn2 + b2) ----
        f32x4 a1[4][2];
#pragma unroll
        for (int rg = 0; rg < 4; ++rg)
#pragma unroll
            for (int t = 0; t < 2; ++t) a1[rg][t] = {0.f, 0.f, 0.f, 0.f};
#pragma unroll
        for (int rg = 0; rg < 4; ++rg) {
            const int R = rg * 16 + lr;
#pragma unroll
            for (int ks = 0; ks < KS; ++ks) {
                const int cs = (ks * 4 + lk) ^ (R & 7);
                s16x8 ax = (s16x8)xs[R][cs];
                s16x8 ag = (s16x8)gs[R][cs];
#pragma unroll
                for (int t = 0; t < 2; ++t) {
                    a1[rg][t] = __builtin_amdgcn_mfma_f32_16x16x32_bf16(ax, bws2[t][ks], a1[rg][t], 0, 0, 0);
                    a1[rg][t] = __builtin_amdgcn_mfma_f32_16x16x32_bf16(ag, bwn2[t][ks], a1[rg][t], 0, 0, 0);
                }
            }
        }
        __syncthreads();
#pragma unroll
        for (int rg = 0; rg < 4; ++rg)
#pragma unroll
            for (int t = 0; t < 2; ++t) {
                const int h = (w * 2 + t) * 16 + lr;
#pragma unroll
                for (int j = 0; j < 4; ++j) {
                    int r = rg * 16 + lk * 4 + j;
                    st_bf(gs16, r, h, fmaxf(a1[rg][t][j] + bv2[t], 0.f));
                }
            }
        __syncthreads();

        // ---- stage 2: x3 = relu(x2@Wm1 + bm1) ----
        f32x4 a2[4][2];
#pragma unroll
        for (int rg = 0; rg < 4; ++rg)
#pragma unroll
            for (int t = 0; t < 2; ++t) a2[rg][t] = {0.f, 0.f, 0.f, 0.f};
#pragma unroll
        for (int rg = 0; rg < 4; ++rg) {
            const int R = rg * 16 + lr;
#pragma unroll
            for (int ks = 0; ks < KS; ++ks) {
                const int cs = (ks * 4 + lk) ^ (R & 7);
                s16x8 ax = (s16x8)gs[R][cs];
#pragma unroll
                for (int t = 0; t < 2; ++t)
                    a2[rg][t] = __builtin_amdgcn_mfma_f32_16x16x32_bf16(ax, bwm1[t][ks], a2[rg][t], 0, 0, 0);
            }
        }
        __syncthreads();
#pragma unroll
        for (int rg = 0; rg < 4; ++rg)
#pragma unroll
            for (int t = 0; t < 2; ++t) {
                const int h = (w * 2 + t) * 16 + lr;
#pragma unroll
                for (int j = 0; j < 4; ++j) {
                    int r = rg * 16 + lk * 4 + j;
                    st_bf(xs16, r, h, fmaxf(a2[rg][t][j] + bvm1[t], 0.f));
                }
            }
        __syncthreads();

        // ---- stage 3: out = x3@Wm2 + bm2 (fp32, H=64) ----
        f32x4 a3[4];
#pragma unroll
        for (int rg = 0; rg < 4; ++rg) a3[rg] = {0.f, 0.f, 0.f, 0.f};
#pragma unroll
        for (int rg = 0; rg < 4; ++rg) {
            const int R = rg * 16 + lr;
#pragma unroll
            for (int ks = 0; ks < KS; ++ks) {
                const int cs = (ks * 4 + lk) ^ (R & 7);
                s16x8 ax = (s16x8)xs[R][cs];
                a3[rg] = __builtin_amdgcn_mfma_f32_16x16x32_bf16(ax, bwm2[ks], a3[rg], 0, 0, 0);
            }
        }
        const int h3 = w * 16 + lr;
#pragma unroll
        for (int rg = 0; rg < 4; ++rg)
#pragma unroll
            for (int j = 0; j < 4; ++j) {
                int n = row0 + rg * 16 + lk * 4 + j;
                if (n < nn) out[(size_t)n * OUT_F + h3] = a3[rg][j] + bvm2;
            }

        if (tile >= ntiles) break;
    }
}

// ---------------------------------------------------------------------------
extern "C" void kernel_launch(void* const* d_in, const int* in_sizes, int n_in,
                              void* d_out, int out_size, void* d_ws, size_t ws_size,
                              hipStream_t stream) {
    const float* feat = (const float*)d_in[0];
    const float* Wn1  = (const float*)d_in[1];
    const float* Ws1  = (const float*)d_in[2];
    const float* b1   = (const float*)d_in[3];
    const float* Wn2  = (const float*)d_in[4];
    const float* Ws2  = (const float*)d_in[5];
    const float* b2   = (const float*)d_in[6];
    const float* Wm1  = (const float*)d_in[7];
    const float* bm1  = (const float*)d_in[8];
    const float* Wm2  = (const float*)d_in[9];
    const float* bm2  = (const float*)d_in[10];
    const int*   src  = (const int*)d_in[11];
    const int*   dst  = (const int*)d_in[12];

    const int nn = in_sizes[0] / N_IN;    // 100000 (< 2^17, required by pack)
    const int E  = in_sizes[11];          // 1600000

    const int nbuk  = (nn + BKT - 1) / BKT;   // 782 buckets
    const int nba   = (E + EPB - 1) / EPB;    // 261 partition blocks
    const int nhist = nbuk * nba;             // ~204K

    // ---- workspace carve-up (64B-aligned) ----
    char* p = (char*)d_ws;
    auto alloc = [&](size_t bytes) { void* q = p; p += (bytes + 63) & ~(size_t)63; return q; };
    int*      offs     = (int*)alloc((size_t)(nn + 1) * 4);
    int*      partials = (int*)alloc(1024 * 4);
    float*    invd     = (float*)alloc((size_t)nn * 4);
    int*      histT    = (int*)alloc((size_t)nhist * 4);
    unsigned* epk      = (unsigned*)alloc((size_t)E * 4);
    int*      csr_src  = (int*)alloc((size_t)E * 4);
    ushort_t* wsT1     = (ushort_t*)alloc((size_t)N_IN * HID * 2);
    ushort_t* wnT1     = (ushort_t*)alloc((size_t)N_IN * HID * 2);
    ushort_t* wsT2     = (ushort_t*)alloc((size_t)HID * HID * 2);
    ushort_t* wnT2     = (ushort_t*)alloc((size_t)HID * HID * 2);
    ushort_t* wmT1     = (ushort_t*)alloc((size_t)HID * HID * 2);
    ushort_t* wmT2     = (ushort_t*)alloc((size_t)HID * OUT_F * 2);
    ushort_t* featb    = (ushort_t*)alloc((size_t)nn * N_IN * 2);
    uchar_t*  x1q      = (uchar_t*)alloc((size_t)nn * HID);
    ushort_t* x1b      = (ushort_t*)alloc((size_t)nn * HID * 2);
    ushort_t* agg2b    = (ushort_t*)alloc((size_t)nn * HID * 2);
    ushort_t* agg1b    = (ushort_t*)d_out;            // dead after mfma_layer1
    uchar_t*  featq    = (uchar_t*)d_out + (size_t)nn * N_IN * 2;
    // agg1b/featq occupy d_out only until mfma_layer1 completes; tail writes
    // d_out afterwards (same stream, ordered).

    const int ntiles = (nn + 63) / 64;
    const int NB     = ntiles < 768 ? ntiles : 768;
    const int NBT    = ntiles < 512 ? ntiles : 512;
    const int n8     = nn * (N_IN / 8);
    const int BA     = (n8 + 255) / 256;
    const int BB     = BA + (73728 + 255) / 256;
    const int BC     = BB + nba;

    // ---- fused prep: conversions + bucket histograms ----
    prep_kernel<<<BC, 256, 0, stream>>>(
        feat, featb, featq, n8,
        Ws1, Wn1, Ws2, Wn2, Wm1, Wm2,
        wsT1, wnT1, wsT2, wnT2, wmT1, wmT2,
        dst, histT, E, nbuk, nba, BA, BB);

    // ---- scan histT (scan_add folded into consumers) ----
    const int nparts = (nhist + 255) / 256;           // 798 <= 1024
    scan_block<<<nparts, 256, 0, stream>>>(histT, histT, partials, nhist);
    scan_partials<<<1, 1024, 0, stream>>>(partials, nparts);

    // ---- partition + per-bucket CSR build ----
    part_edges<<<nba, 256, 0, stream>>>(src, dst, histT, partials, epk, E, nbuk, nba);
    build_bucket<<<nbuk, 256, 0, stream>>>(epk, histT, partials, offs, invd, csr_src, nn, E, nbuk, nba);

    // ---- layer 1 ----
    gather_fp8<N_IN><<<(nn + 3) / 4, 256, 0, stream>>>(
        featq, csr_src, offs, invd, agg1b, nn);
    mfma_layer<N_IN, HID, true, true, true, true><<<NB, 256, 0, stream>>>(
        featb, agg1b, wsT1, wnT1, b1, x1b, x1q, nn);

    // ---- layer 2 gather ----
    gather_fp8<HID><<<(nn + 3) / 4, 256, 0, stream>>>(
        x1q, csr_src, offs, invd, agg2b, nn);

    // ---- fused tail: SAGE-2 + MLP1 + MLP2 -> d_out ----
    mfma_tail<<<NBT, 256, 0, stream>>>(
        x1b, agg2b, wsT2, wnT2, wmT1, wmT2, b2, bm1, bm2, (float*)d_out, nn);
}